// Round 1
// baseline (341.370 us; speedup 1.0000x reference)
//
#include <hip/hip_runtime.h>
#include <hip/hip_bf16.h>

#define SEQ 4096
#define DIM 1024

using f32x4  = __attribute__((ext_vector_type(4))) float;
using bf16x8 = __attribute__((ext_vector_type(8))) short;

static __device__ __forceinline__ float bf2f(unsigned short u) {
  unsigned int x = ((unsigned int)u) << 16;
  return __builtin_bit_cast(float, x);
}
static __device__ __forceinline__ unsigned short f2bf(float f) {
  unsigned int x = __builtin_bit_cast(unsigned int, f);
  unsigned int r = (x + 0x7fff + ((x >> 16) & 1)) >> 16;  // RNE
  return (unsigned short)r;
}

// ---- convert x -> bf16, and copy x into out[:, 0:1024] (fp32 exact) ----
__global__ __launch_bounds__(256) void convert_x_kernel(
    const float* __restrict__ x, unsigned short* __restrict__ xb,
    float* __restrict__ out) {
  int idx = blockIdx.x * 256 + threadIdx.x;  // one thread per 4 floats
  int e = idx * 4;
  int i = e >> 10;
  int d = e & 1023;
  float4 v = *(const float4*)(x + (size_t)e);
  *(float4*)(out + (size_t)i * 2048 + d) = v;
  ushort4 p;
  p.x = f2bf(v.x); p.y = f2bf(v.y); p.z = f2bf(v.z); p.w = f2bf(v.w);
  *(ushort4*)(xb + (size_t)e) = p;
}

// ---- transpose fp32 [R][C] -> bf16 [C][R] ----
__global__ __launch_bounds__(256) void transpose_f32_to_bf16(
    const float* __restrict__ in, unsigned short* __restrict__ out, int R, int C) {
  __shared__ float tile[32][33];
  int bx = blockIdx.x * 32;  // col base
  int by = blockIdx.y * 32;  // row base
  int tx = threadIdx.x & 31;
  int ty = threadIdx.x >> 5;  // 0..7
#pragma unroll
  for (int r = 0; r < 32; r += 8)
    tile[ty + r][tx] = in[(size_t)(by + ty + r) * C + bx + tx];
  __syncthreads();
#pragma unroll
  for (int r = 0; r < 32; r += 8)
    out[(size_t)(bx + ty + r) * R + by + tx] = f2bf(tile[tx][ty + r]);
}

// ---- transpose bf16 [R][C] -> bf16 [C][R] ----
__global__ __launch_bounds__(256) void transpose_bf16(
    const unsigned short* __restrict__ in, unsigned short* __restrict__ out,
    int R, int C) {
  __shared__ unsigned short tile[32][33];
  int bx = blockIdx.x * 32;
  int by = blockIdx.y * 32;
  int tx = threadIdx.x & 31;
  int ty = threadIdx.x >> 5;
#pragma unroll
  for (int r = 0; r < 32; r += 8)
    tile[ty + r][tx] = in[(size_t)(by + ty + r) * C + bx + tx];
  __syncthreads();
#pragma unroll
  for (int r = 0; r < 32; r += 8)
    out[(size_t)(bx + ty + r) * R + by + tx] = tile[tx][ty + r];
}

// ---- BT GEMM: C[M][N] = A[M][K] * B[N][K]^T (+bias)*scale ----
// MODE 0: plain. MODE 1: scores (skip tiles entirely below diagonal).
// MODE 2: PV (K-loop starts at k = i0; A rows have zeros for k<i).
// OUTBF 1: bf16 output to Cb. OUTBF 0: fp32 output to Cf at col offset ccol.
template <int MODE, int OUTBF>
__global__ __launch_bounds__(256) void gemm_bt(
    const unsigned short* __restrict__ A, int lda,
    const unsigned short* __restrict__ B, int ldb,
    const float* __restrict__ bias, float scale,
    unsigned short* __restrict__ Cb, float* __restrict__ Cf,
    int ldc, int ccol, int K) {
  const int tid  = threadIdx.x;
  const int wave = tid >> 6;
  const int lane = tid & 63;
  const int wm = wave >> 1, wn = wave & 1;
  const int i0 = blockIdx.y * 128;
  const int j0 = blockIdx.x * 128;
  if (MODE == 1 && (j0 + 128) <= i0) return;  // fully-masked tile
  const int kstart = (MODE == 2) ? i0 : 0;

  __shared__ unsigned short lA[128 * 32];  // 8 KB
  __shared__ unsigned short lB[128 * 32];  // 8 KB

  f32x4 acc[4][4];
#pragma unroll
  for (int a = 0; a < 4; ++a)
#pragma unroll
    for (int b = 0; b < 4; ++b) acc[a][b] = (f32x4){0.f, 0.f, 0.f, 0.f};

  const int l15  = lane & 15;
  const int quad = lane >> 4;

  for (int kt = kstart; kt < K; kt += 32) {
    // stage A[128][32], B[128][32]: 512 chunks of 16B each, 2 per thread
#pragma unroll
    for (int it = 0; it < 2; ++it) {
      int c  = it * 256 + tid;
      int r  = c >> 2;
      int co = (c & 3) << 3;
      *(float4*)(&lA[c * 8]) = *(const float4*)(A + (size_t)(i0 + r) * lda + kt + co);
      *(float4*)(&lB[c * 8]) = *(const float4*)(B + (size_t)(j0 + r) * ldb + kt + co);
    }
    __syncthreads();
    bf16x8 af[4], bfr[4];
#pragma unroll
    for (int mt = 0; mt < 4; ++mt)
      af[mt] = *(const bf16x8*)&lA[(wm * 64 + mt * 16 + l15) * 32 + quad * 8];
#pragma unroll
    for (int nt = 0; nt < 4; ++nt)
      bfr[nt] = *(const bf16x8*)&lB[(wn * 64 + nt * 16 + l15) * 32 + quad * 8];
#pragma unroll
    for (int mt = 0; mt < 4; ++mt)
#pragma unroll
      for (int nt = 0; nt < 4; ++nt)
        acc[mt][nt] = __builtin_amdgcn_mfma_f32_16x16x32_bf16(af[mt], bfr[nt], acc[mt][nt], 0, 0, 0);
    __syncthreads();
  }

  // epilogue: C/D layout col=lane&15, row=quad*4+reg
#pragma unroll
  for (int nt = 0; nt < 4; ++nt) {
    int gc = j0 + wn * 64 + nt * 16 + l15;
    float bv = bias ? bias[gc] : 0.0f;
#pragma unroll
    for (int mt = 0; mt < 4; ++mt) {
      int gr0 = i0 + wm * 64 + mt * 16 + quad * 4;
#pragma unroll
      for (int r = 0; r < 4; ++r) {
        float v = (acc[mt][nt][r] + bv) * scale;
        if (OUTBF)
          Cb[(size_t)(gr0 + r) * ldc + gc] = f2bf(v);
        else
          Cf[(size_t)(gr0 + r) * ldc + ccol + gc] = v;
      }
    }
  }
}

// ---- row softmax with anti-causal mask (keep j >= i), in place bf16 ----
__global__ __launch_bounds__(256) void softmax_kernel(unsigned short* __restrict__ sc) {
  const int i    = blockIdx.x;  // row
  const int tid  = threadIdx.x;
  const int lane = tid & 63;
  const int wave = tid >> 6;
  unsigned short* row = sc + (size_t)i * SEQ;

  float vals[16];
  float m = -1e30f;
#pragma unroll
  for (int h = 0; h < 2; ++h) {
    int j0 = (h * 256 + tid) * 8;
    ushort4 r0 = *(const ushort4*)(row + j0);
    ushort4 r1 = *(const ushort4*)(row + j0 + 4);
    unsigned short u[8] = {r0.x, r0.y, r0.z, r0.w, r1.x, r1.y, r1.z, r1.w};
#pragma unroll
    for (int e = 0; e < 8; ++e) {
      float f = bf2f(u[e]);
      vals[h * 8 + e] = f;
      if (j0 + e >= i) m = fmaxf(m, f);
    }
  }
#pragma unroll
  for (int o = 32; o > 0; o >>= 1) m = fmaxf(m, __shfl_xor(m, o));
  __shared__ float redm[4], redl[4];
  if (lane == 0) redm[wave] = m;
  __syncthreads();
  m = fmaxf(fmaxf(redm[0], redm[1]), fmaxf(redm[2], redm[3]));

  float l = 0.f;
#pragma unroll
  for (int h = 0; h < 2; ++h) {
#pragma unroll
    for (int e = 0; e < 8; ++e) {
      int j = (h * 256 + tid) * 8 + e;
      float ev = (j >= i) ? __expf(vals[h * 8 + e] - m) : 0.f;
      vals[h * 8 + e] = ev;
      l += ev;
    }
  }
#pragma unroll
  for (int o = 32; o > 0; o >>= 1) l += __shfl_xor(l, o);
  if (lane == 0) redl[wave] = l;
  __syncthreads();
  l = redl[0] + redl[1] + redl[2] + redl[3];
  float inv = 1.0f / l;

#pragma unroll
  for (int h = 0; h < 2; ++h) {
    int j0 = (h * 256 + tid) * 8;
    ushort4 o0, o1;
    o0.x = f2bf(vals[h * 8 + 0] * inv);
    o0.y = f2bf(vals[h * 8 + 1] * inv);
    o0.z = f2bf(vals[h * 8 + 2] * inv);
    o0.w = f2bf(vals[h * 8 + 3] * inv);
    o1.x = f2bf(vals[h * 8 + 4] * inv);
    o1.y = f2bf(vals[h * 8 + 5] * inv);
    o1.z = f2bf(vals[h * 8 + 6] * inv);
    o1.w = f2bf(vals[h * 8 + 7] * inv);
    *(ushort4*)(row + j0)     = o0;
    *(ushort4*)(row + j0 + 4) = o1;
  }
}

extern "C" void kernel_launch(void* const* d_in, const int* in_sizes, int n_in,
                              void* d_out, int out_size, void* d_ws, size_t ws_size,
                              hipStream_t stream) {
  const float* x  = (const float*)d_in[0];
  const float* Wk = (const float*)d_in[1];
  const float* bk = (const float*)d_in[2];
  const float* Wq = (const float*)d_in[3];
  const float* bq = (const float*)d_in[4];
  const float* Wv = (const float*)d_in[5];
  const float* bv = (const float*)d_in[6];
  float* out = (float*)d_out;

  char* ws = (char*)d_ws;
  unsigned short* Xb  = (unsigned short*)(ws);                  // 8 MB  [4096][1024]
  unsigned short* Wtq = (unsigned short*)(ws + (8ull << 20));   // 2 MB  [1024][1024]
  unsigned short* Wtk = Wtq + 1024 * 1024;                      // 2 MB
  unsigned short* Wtv = Wtk + 1024 * 1024;                      // 2 MB
  unsigned short* Qb  = (unsigned short*)(ws + (14ull << 20));  // 8 MB  [4096][1024]
  unsigned short* Kb  = (unsigned short*)(ws + (22ull << 20));  // 8 MB
  unsigned short* Vb  = (unsigned short*)(ws + (30ull << 20));  // 8 MB
  unsigned short* Vt  = (unsigned short*)(ws + (38ull << 20));  // 8 MB  [1024][4096]
  unsigned short* Pr  = (unsigned short*)(ws + (46ull << 20));  // 32 MB [4096][4096]

  // 1. x -> bf16 ; out[:, :1024] = x
  convert_x_kernel<<<SEQ * DIM / 4 / 256, 256, 0, stream>>>(x, Xb, out);

  // 2. W transposes ([in][out] fp32 -> [out][in] bf16)
  dim3 tg(DIM / 32, DIM / 32);
  transpose_f32_to_bf16<<<tg, 256, 0, stream>>>(Wq, Wtq, DIM, DIM);
  transpose_f32_to_bf16<<<tg, 256, 0, stream>>>(Wk, Wtk, DIM, DIM);
  transpose_f32_to_bf16<<<tg, 256, 0, stream>>>(Wv, Wtv, DIM, DIM);

  // 3. QKV GEMMs (Q folds 1/sqrt(1024) into output incl. bias)
  dim3 gq(DIM / 128, SEQ / 128);
  gemm_bt<0, 1><<<gq, 256, 0, stream>>>(Xb, DIM, Wtq, DIM, bq, 1.0f / 32.0f, Qb, nullptr, DIM, 0, DIM);
  gemm_bt<0, 1><<<gq, 256, 0, stream>>>(Xb, DIM, Wtk, DIM, bk, 1.0f, Kb, nullptr, DIM, 0, DIM);
  gemm_bt<0, 1><<<gq, 256, 0, stream>>>(Xb, DIM, Wtv, DIM, bv, 1.0f, Vb, nullptr, DIM, 0, DIM);

  // 4. V transpose for BT PV gemm
  transpose_bf16<<<dim3(DIM / 32, SEQ / 32), 256, 0, stream>>>(Vb, Vt, SEQ, DIM);

  // 5. scores = Qs @ K^T (bf16, upper tiles only)
  gemm_bt<1, 1><<<dim3(SEQ / 128, SEQ / 128), 256, 0, stream>>>(
      Qb, DIM, Kb, DIM, nullptr, 1.0f, Pr, nullptr, SEQ, 0, DIM);

  // 6. masked row softmax in place -> probs bf16
  softmax_kernel<<<SEQ, 256, 0, stream>>>(Pr);

  // 7. read = probs @ V -> out[:, 1024:2048] (fp32), K-loop starts at diagonal
  gemm_bt<2, 0><<<dim3(DIM / 128, SEQ / 128), 256, 0, stream>>>(
      Pr, SEQ, Vt, SEQ, nullptr, 1.0f, nullptr, out, 2048, 1024, SEQ);
}

// Round 2
// 244.550 us; speedup vs baseline: 1.3959x; 1.3959x over previous
//
#include <hip/hip_runtime.h>
#include <hip/hip_bf16.h>

#define SEQ 4096
#define DIM 1024

using f32x4  = __attribute__((ext_vector_type(4))) float;
using bf16x8 = __attribute__((ext_vector_type(8))) short;

static __device__ __forceinline__ float bf2f(unsigned short u) {
  unsigned int x = ((unsigned int)u) << 16;
  return __builtin_bit_cast(float, x);
}
static __device__ __forceinline__ unsigned short f2bf(float f) {
  unsigned int x = __builtin_bit_cast(unsigned int, f);
  unsigned int r = (x + 0x7fff + ((x >> 16) & 1)) >> 16;  // RNE
  return (unsigned short)r;
}

// ---- x -> bf16; out[:, :1024] = x (fp32); out[:, 1024:2048] = 0 ----
__global__ __launch_bounds__(256) void convert_x_kernel(
    const float* __restrict__ x, unsigned short* __restrict__ xb,
    float* __restrict__ out) {
  int idx = blockIdx.x * 256 + threadIdx.x;  // one thread per 4 floats
  int e = idx * 4;
  int i = e >> 10;
  int d = e & 1023;
  float4 v = *(const float4*)(x + (size_t)e);
  *(float4*)(out + (size_t)i * 2048 + d) = v;
  *(float4*)(out + (size_t)i * 2048 + 1024 + d) = make_float4(0.f, 0.f, 0.f, 0.f);
  ushort4 p;
  p.x = f2bf(v.x); p.y = f2bf(v.y); p.z = f2bf(v.z); p.w = f2bf(v.w);
  *(ushort4*)(xb + (size_t)e) = p;
}

// ---- transpose fp32 [R][C] -> bf16 [C][R] (square-ish, 32x32 tiles) ----
__global__ __launch_bounds__(256) void transpose_f32_to_bf16(
    const float* __restrict__ in, unsigned short* __restrict__ out, int R, int C) {
  __shared__ float tile[32][33];
  int bx = blockIdx.x * 32;  // col base
  int by = blockIdx.y * 32;  // row base
  int tx = threadIdx.x & 31;
  int ty = threadIdx.x >> 5;  // 0..7
#pragma unroll
  for (int r = 0; r < 32; r += 8)
    tile[ty + r][tx] = in[(size_t)(by + ty + r) * C + bx + tx];
  __syncthreads();
#pragma unroll
  for (int r = 0; r < 32; r += 8)
    out[(size_t)(bx + ty + r) * R + by + tx] = f2bf(tile[tx][ty + r]);
}

// ---- transpose bf16: out[c][r] = in[r*ld_in + c] ; r<R, c<C ----
__global__ __launch_bounds__(256) void transpose_bf16_strided(
    const unsigned short* __restrict__ in, int ld_in,
    unsigned short* __restrict__ out, int ld_out, int R, int C) {
  __shared__ unsigned short tile[32][33];
  int bx = blockIdx.x * 32;  // c base
  int by = blockIdx.y * 32;  // r base
  int tx = threadIdx.x & 31;
  int ty = threadIdx.x >> 5;
#pragma unroll
  for (int r = 0; r < 32; r += 8)
    tile[ty + r][tx] = in[(size_t)(by + ty + r) * ld_in + bx + tx];
  __syncthreads();
#pragma unroll
  for (int r = 0; r < 32; r += 8)
    out[(size_t)(bx + ty + r) * ld_out + by + tx] = tile[tx][ty + r];
}

// ---- bias concat [bq | bk | bv] -> bcat[3072] ----
__global__ __launch_bounds__(256) void concat_bias_kernel(
    const float* __restrict__ bq, const float* __restrict__ bk,
    const float* __restrict__ bv, float* __restrict__ bcat) {
  int i = blockIdx.x * 256 + threadIdx.x;
  float v = (i < 1024) ? bq[i] : (i < 2048 ? bk[i - 1024] : bv[i - 2048]);
  bcat[i] = v;
}

// ---- BT GEMM: C[M][N] = A[M][K] * B[N][K]^T, global_load_lds staging ----
// MODE 0: fused QKV. bias=bcat, per-col scale (1/32 for gc<1024), bf16 out.
// MODE 1: scores. compact upper-tri grid (blockIdx.x linear), bf16 out.
// MODE 2: PV split-K. blockIdx.z = K-chunk of 1024; fp32 atomicAdd out.
template <int MODE>
__global__ __launch_bounds__(256) void gemm_bt(
    const unsigned short* __restrict__ A, int lda,
    const unsigned short* __restrict__ B, int ldb,
    const float* __restrict__ bias,
    unsigned short* __restrict__ Cb, float* __restrict__ Cf,
    int ldc, int ccol, int K) {
  const int tid  = threadIdx.x;
  const int wave = tid >> 6;
  const int lane = tid & 63;
  const int wm = wave >> 1, wn = wave & 1;

  int i0, j0, kstart, kend;
  if (MODE == 1) {
    // map linear t -> (bi, bj), bj >= bi, 32x32 tile triangle (528 blocks)
    int t = blockIdx.x;
    int bi = (int)floorf((65.0f - sqrtf(4225.0f - 8.0f * (float)t)) * 0.5f);
    while (bi > 0 && (bi * (65 - bi)) / 2 > t) --bi;
    while (((bi + 1) * (64 - bi)) / 2 <= t) ++bi;
    int bj = bi + (t - (bi * (65 - bi)) / 2);
    i0 = bi * 128; j0 = bj * 128; kstart = 0; kend = K;
  } else if (MODE == 2) {
    i0 = blockIdx.y * 128; j0 = blockIdx.x * 128;
    int kc0 = blockIdx.z * 1024;
    kend = kc0 + 1024;
    if (kend <= i0) return;           // chunk entirely in zero region
    kstart = (kc0 > i0) ? kc0 : i0;   // Pr cols < i0 are exactly zero
  } else {
    i0 = blockIdx.y * 128; j0 = blockIdx.x * 128; kstart = 0; kend = K;
  }

  __shared__ unsigned short lA[128 * 32];  // 8 KB
  __shared__ unsigned short lB[128 * 32];  // 8 KB

  f32x4 acc[4][4];
#pragma unroll
  for (int a = 0; a < 4; ++a)
#pragma unroll
    for (int b = 0; b < 4; ++b) acc[a][b] = (f32x4){0.f, 0.f, 0.f, 0.f};

  const int l15  = lane & 15;
  const int quad = lane >> 4;
  const int cbase = wave * 128;  // this wave stages chunks [cbase, cbase+128)

  for (int kt = kstart; kt < kend; kt += 32) {
    const unsigned short* gA = A + (size_t)i0 * lda + kt;
    const unsigned short* gB = B + (size_t)j0 * ldb + kt;
#pragma unroll
    for (int t = 0; t < 2; ++t) {
      int c  = cbase + t * 64 + lane;
      int r  = c >> 2;
      int co = (c & 3) << 3;
      __builtin_amdgcn_global_load_lds(
          (const __attribute__((address_space(1))) void*)(gA + (size_t)r * lda + co),
          (__attribute__((address_space(3))) void*)(&lA[(cbase + t * 64) * 8]),
          16, 0, 0);
      __builtin_amdgcn_global_load_lds(
          (const __attribute__((address_space(1))) void*)(gB + (size_t)r * ldb + co),
          (__attribute__((address_space(3))) void*)(&lB[(cbase + t * 64) * 8]),
          16, 0, 0);
    }
    __syncthreads();
    bf16x8 af[4], bfr[4];
#pragma unroll
    for (int mt = 0; mt < 4; ++mt)
      af[mt] = *(const bf16x8*)&lA[(wm * 64 + mt * 16 + l15) * 32 + quad * 8];
#pragma unroll
    for (int nt = 0; nt < 4; ++nt)
      bfr[nt] = *(const bf16x8*)&lB[(wn * 64 + nt * 16 + l15) * 32 + quad * 8];
#pragma unroll
    for (int mt = 0; mt < 4; ++mt)
#pragma unroll
      for (int nt = 0; nt < 4; ++nt)
        acc[mt][nt] = __builtin_amdgcn_mfma_f32_16x16x32_bf16(af[mt], bfr[nt], acc[mt][nt], 0, 0, 0);
    __syncthreads();
  }

  // epilogue: C/D layout col=lane&15, row=quad*4+reg
#pragma unroll
  for (int nt = 0; nt < 4; ++nt) {
    int gc = j0 + wn * 64 + nt * 16 + l15;
    float bv = (MODE == 0) ? bias[gc] : 0.0f;
    float scale = (MODE == 0) ? ((gc < 1024) ? 0.03125f : 1.0f) : 1.0f;
#pragma unroll
    for (int mt = 0; mt < 4; ++mt) {
      int gr0 = i0 + wm * 64 + mt * 16 + quad * 4;
#pragma unroll
      for (int r = 0; r < 4; ++r) {
        float v = (acc[mt][nt][r] + bv) * scale;
        if (MODE == 2)
          unsafeAtomicAdd(&Cf[(size_t)(gr0 + r) * ldc + ccol + gc], v);
        else
          Cb[(size_t)(gr0 + r) * ldc + gc] = f2bf(v);
      }
    }
  }
}

// ---- row softmax with anti-causal mask (keep j >= i), in place bf16 ----
__global__ __launch_bounds__(256) void softmax_kernel(unsigned short* __restrict__ sc) {
  const int i    = blockIdx.x;  // row
  const int tid  = threadIdx.x;
  const int lane = tid & 63;
  const int wave = tid >> 6;
  unsigned short* row = sc + (size_t)i * SEQ;

  float vals[16];
  float m = -1e30f;
#pragma unroll
  for (int h = 0; h < 2; ++h) {
    int j0 = (h * 256 + tid) * 8;
    ushort4 r0 = *(const ushort4*)(row + j0);
    ushort4 r1 = *(const ushort4*)(row + j0 + 4);
    unsigned short u[8] = {r0.x, r0.y, r0.z, r0.w, r1.x, r1.y, r1.z, r1.w};
#pragma unroll
    for (int e = 0; e < 8; ++e) {
      float f = bf2f(u[e]);
      vals[h * 8 + e] = f;
      if (j0 + e >= i) m = fmaxf(m, f);
    }
  }
#pragma unroll
  for (int o = 32; o > 0; o >>= 1) m = fmaxf(m, __shfl_xor(m, o));
  __shared__ float redm[4], redl[4];
  if (lane == 0) redm[wave] = m;
  __syncthreads();
  m = fmaxf(fmaxf(redm[0], redm[1]), fmaxf(redm[2], redm[3]));

  float l = 0.f;
#pragma unroll
  for (int h = 0; h < 2; ++h) {
#pragma unroll
    for (int e = 0; e < 8; ++e) {
      int j = (h * 256 + tid) * 8 + e;
      float ev = (j >= i) ? __expf(vals[h * 8 + e] - m) : 0.f;
      vals[h * 8 + e] = ev;
      l += ev;
    }
  }
#pragma unroll
  for (int o = 32; o > 0; o >>= 1) l += __shfl_xor(l, o);
  if (lane == 0) redl[wave] = l;
  __syncthreads();
  l = redl[0] + redl[1] + redl[2] + redl[3];
  float inv = 1.0f / l;

#pragma unroll
  for (int h = 0; h < 2; ++h) {
    int j0 = (h * 256 + tid) * 8;
    ushort4 o0, o1;
    o0.x = f2bf(vals[h * 8 + 0] * inv);
    o0.y = f2bf(vals[h * 8 + 1] * inv);
    o0.z = f2bf(vals[h * 8 + 2] * inv);
    o0.w = f2bf(vals[h * 8 + 3] * inv);
    o1.x = f2bf(vals[h * 8 + 4] * inv);
    o1.y = f2bf(vals[h * 8 + 5] * inv);
    o1.z = f2bf(vals[h * 8 + 6] * inv);
    o1.w = f2bf(vals[h * 8 + 7] * inv);
    *(ushort4*)(row + j0)     = o0;
    *(ushort4*)(row + j0 + 4) = o1;
  }
}

extern "C" void kernel_launch(void* const* d_in, const int* in_sizes, int n_in,
                              void* d_out, int out_size, void* d_ws, size_t ws_size,
                              hipStream_t stream) {
  const float* x  = (const float*)d_in[0];
  const float* Wk = (const float*)d_in[1];
  const float* bk = (const float*)d_in[2];
  const float* Wq = (const float*)d_in[3];
  const float* bq = (const float*)d_in[4];
  const float* Wv = (const float*)d_in[5];
  const float* bv = (const float*)d_in[6];
  float* out = (float*)d_out;

  char* ws = (char*)d_ws;
  unsigned short* Xb   = (unsigned short*)(ws);                  // 8 MB  [4096][1024]
  unsigned short* Wcat = (unsigned short*)(ws + (8ull << 20));   // 6 MB  [3072][1024] (Q|K|V rows)
  unsigned short* QKVb = (unsigned short*)(ws + (14ull << 20));  // 24 MB [4096][3072]
  unsigned short* Vt   = (unsigned short*)(ws + (38ull << 20));  // 8 MB  [1024][4096]
  unsigned short* Pr   = (unsigned short*)(ws + (46ull << 20));  // 32 MB [4096][4096]
  float*          bcat = (float*)(ws + (46ull << 20));           // 12 KB, aliases Pr (dead by then)

  // 1. x -> bf16 ; out[:, :1024] = x ; out[:, 1024:] = 0
  convert_x_kernel<<<SEQ * DIM / 4 / 256, 256, 0, stream>>>(x, Xb, out);

  // 2. W transposes ([in][out] fp32 -> [out][in] bf16) into Wcat sections
  dim3 tg(DIM / 32, DIM / 32);
  transpose_f32_to_bf16<<<tg, 256, 0, stream>>>(Wq, Wcat + 0 * DIM * DIM, DIM, DIM);
  transpose_f32_to_bf16<<<tg, 256, 0, stream>>>(Wk, Wcat + 1 * DIM * DIM, DIM, DIM);
  transpose_f32_to_bf16<<<tg, 256, 0, stream>>>(Wv, Wcat + 2 * DIM * DIM, DIM, DIM);
  concat_bias_kernel<<<12, 256, 0, stream>>>(bq, bk, bv, bcat);

  // 3. fused QKV GEMM: [4096][3072] = Xb @ Wcat^T (+bcat, Q cols scaled 1/32)
  gemm_bt<0><<<dim3(3072 / 128, SEQ / 128), 256, 0, stream>>>(
      Xb, DIM, Wcat, DIM, bcat, QKVb, nullptr, 3072, 0, DIM);

  // 4. Vt[1024][4096] = transpose of V (= QKVb cols 2048:3072)
  transpose_bf16_strided<<<dim3(DIM / 32, SEQ / 32), 256, 0, stream>>>(
      QKVb + 2048, 3072, Vt, SEQ, SEQ, DIM);

  // 5. scores upper-tri tiles: Pr = Qs @ K^T  (528 blocks)
  gemm_bt<1><<<528, 256, 0, stream>>>(
      QKVb, 3072, QKVb + 1024, 3072, nullptr, Pr, nullptr, SEQ, 0, DIM);

  // 6. masked row softmax in place -> probs bf16 (zeros below diagonal)
  softmax_kernel<<<SEQ, 256, 0, stream>>>(Pr);

  // 7. read = probs @ V -> out[:, 1024:2048] (fp32 atomic, split-K x4)
  gemm_bt<2><<<dim3(DIM / 128, SEQ / 128, 4), 256, 0, stream>>>(
      Pr, SEQ, Vt, SEQ, nullptr, nullptr, out, 2048, 1024, SEQ);
}